// Round 20
// baseline (431.619 us; speedup 1.0000x reference)
//
#include <hip/hip_runtime.h>
#include <math.h>

// Problem constants
#define NB 8
#define NT 2048
#define NC 128
#define NLM 64
#define NS 4
#define QROWS 2049
#define NCH 32  // 2048 / 64 chunks

#define TWO_LOG2E 2.885390081777927f
#define LOG2E_F 1.4426950408889634f

typedef __attribute__((__ext_vector_type__(8))) short short8v;   // 8 bf16
typedef __attribute__((__ext_vector_type__(4))) float f32x4v;    // MFMA acc

__device__ __forceinline__ float rcp_fast(float x) {
  return __builtin_amdgcn_rcpf(x);
}

__device__ __forceinline__ float readlane_f(float v, int lane) {
  return __int_as_float(__builtin_amdgcn_readlane(__float_as_int(v), lane));
}

// Raw v_exp_f32 (2^x). Safe here: |y| bounded ~12.
__device__ __forceinline__ float exp2_fast(float x) {
  float r;
  asm("v_exp_f32 %0, %1" : "=v"(r) : "v"(x));
  return r;
}

// HW trig in revolutions with REQUIRED v_fract reduction (R27, verified).
__device__ __forceinline__ float fract_fast(float x) {
  float r;
  asm("v_fract_f32 %0, %1" : "=v"(r) : "v"(x));
  return r;
}
__device__ __forceinline__ float sin_rev(float r) {
  float d;
  asm("v_sin_f32 %0, %1" : "=v"(d) : "v"(r));
  return d;
}
__device__ __forceinline__ float cos_rev(float r) {
  float d;
  asm("v_cos_f32 %0, %1" : "=v"(d) : "v"(r));
  return d;
}

// bf16 hi/lo split by truncation: v = hi + lo with |err| ~ 2^-16 |v|.
__device__ __forceinline__ void bf16_split(float v, unsigned short* h,
                                           unsigned short* l) {
  unsigned vb = __float_as_uint(v);
  unsigned short hi = (unsigned short)(vb >> 16);
  float hf = __uint_as_float((unsigned)hi << 16);
  float lo = v - hf;  // exact
  *h = hi;
  *l = (unsigned short)(__float_as_uint(lo) >> 16);
}

// ---------------------------------------------------------------------------
// Tiled 64-step local linear scan (forward substitution); all indices
// compile-time so q[4][16] stays in VGPRs. (Used by k23's logZ branch.)
// ---------------------------------------------------------------------------
template <typename PF, typename DF>
__device__ __forceinline__ void tri_scan64(PF P, DF D, float q[4][16]) {
#pragma unroll
  for (int tau = 0; tau < 4; ++tau) {
    float acc[16];
#pragma unroll
    for (int i = 0; i < 16; ++i) acc[i] = D(tau * 16 + i);
#pragma unroll
    for (int p = 0; p < 4; ++p) {
      if (p < tau) {
#pragma unroll
        for (int i = 0; i < 16; ++i) {
          const int t = tau * 16 + i;
#pragma unroll
          for (int i2 = 0; i2 < 16; ++i2) {
            acc[i] = fmaf(P(t, t - (p * 16 + i2) - 1), q[p][i2], acc[i]);
          }
        }
      }
    }
#pragma unroll
    for (int i = 0; i < 16; ++i) {
      const int t = tau * 16 + i;
#pragma unroll
      for (int i2 = 0; i2 < 16; ++i2) {
        if (i2 < i) acc[i] = fmaf(P(t, i - i2 - 1), q[tau][i2], acc[i]);
      }
      q[tau][i] = acc[i];
    }
  }
}

// K1 v3 (R27, measured): R22 structure + fract-reduced HW trig.
__global__ __launch_bounds__(256) void k1_uv(
    const float* __restrict__ x, const float* __restrict__ W,
    const float* __restrict__ bias, const float* __restrict__ phiw,
    float* __restrict__ Q) {
  __shared__ __align__(16) float xs[16][128];  // 8 KB
  __shared__ float us[16][256];                // 16 KB
  const int tid = threadIdx.x;
  const int j = tid & 127;  // column
  const int h = tid >> 7;   // row-half: rows h*8 .. h*8+7
  const int r0 = h * 8;
  const int bt0 = blockIdx.x * 16;
  {
    const float4* x4 = (const float4*)(x + (long)bt0 * NC);
    ((float4*)xs)[tid] = x4[tid];
    ((float4*)xs)[tid + 256] = x4[tid + 256];
  }
  __syncthreads();
  float z[8];
  const float bj = bias[j];
#pragma unroll
  for (int r = 0; r < 8; ++r) z[r] = bj;
  for (int k = 0; k < 128; ++k) {
    float w = W[k * 128 + j];
#pragma unroll
    for (int r = 0; r < 8; ++r) z[r] = fmaf(xs[r0 + r][k], w, z[r]);
  }
  const float rs = 0.08838834764831845f;   // 1/sqrt(128)
  const float inv2pi = 0.15915494309189535f;  // 1/(2*pi)
#pragma unroll
  for (int r = 0; r < 8; ++r) {
    float rf = fract_fast(z[r] * inv2pi);  // revolutions, reduced to [0,1)
    us[r0 + r][j] = cos_rev(rf) * rs;
    us[r0 + r][128 + j] = sin_rev(rf) * rs;
  }
  __syncthreads();
  float a[8];
#pragma unroll
  for (int r = 0; r < 8; ++r) a[r] = 0.f;
  for (int k = 0; k < 256; ++k) {
    float w = phiw[k * 128 + j];
#pragma unroll
    for (int r = 0; r < 8; ++r) a[r] = fmaf(us[r0 + r][k], w, a[r]);
  }
#pragma unroll
  for (int r = 0; r < 8; ++r) {
    int bt = bt0 + r0 + r;
    int b = bt >> 11, t = bt & 2047;
    Q[(b * QROWS + t + 1) * NC + j] = a[r];
  }
}

// K23 merged: blocks 0..255 = k2a (per-chunk raw sums of V);
//             blocks 256..259 = k3ab (serial logZ chunk evolution, per s).
__global__ __launch_bounds__(128) void k23_sums_logz(
    const float* __restrict__ Q, float* __restrict__ S2,
    const float* __restrict__ logw, float* __restrict__ logZt) {
  __shared__ float4 part[4][32];
  __shared__ float wx[64];
  __shared__ float mTs[64][65];
  __shared__ float Zr[64];
  const int x = blockIdx.x;
  const int tid = threadIdx.x;
  if (x < 256) {
    const int b = x >> 5, ch = x & 31;
    const int g = tid >> 5, c4 = tid & 31;
    const float4* Q4 = (const float4*)(Q + (long)(b * QROWS + ch * 64 + 1) * NC);
    float4 acc = make_float4(0.f, 0.f, 0.f, 0.f);
#pragma unroll
    for (int i = 0; i < 16; ++i) {
      float4 v = Q4[(g * 16 + i) * 32 + c4];
      acc.x += v.x; acc.y += v.y; acc.z += v.z; acc.w += v.w;
    }
    part[g][c4] = acc;
    __syncthreads();
    if (g == 0) {
      float4 p0 = part[0][c4], p1 = part[1][c4], p2 = part[2][c4], p3 = part[3][c4];
      ((float4*)(S2 + (long)(b * NCH + ch) * NC))[c4] =
          make_float4(p0.x + p1.x + p2.x + p3.x, p0.y + p1.y + p2.y + p3.y,
                      p0.z + p1.z + p2.z + p3.z, p0.w + p1.w + p2.w + p3.w);
    }
  } else {
    const int s = x - 256;
    const int j = tid;
    if (j < 64) wx[j] = __expf(logw[s * NLM + j]);
    __syncthreads();
    if (j < 64) {
      float q[4][16];
      tri_scan64([&](int t, int l) { return wx[l]; },
                 [&](int t) { int l = t + j; return (l < 64) ? wx[l] : 0.f; }, q);
#pragma unroll
      for (int tau = 0; tau < 4; ++tau)
#pragma unroll
        for (int i = 0; i < 16; ++i) mTs[j][tau * 16 + i] = q[tau][i];
    }
    const int t = j;
    if (t < 64) Zr[t] = (t == 0) ? 1.f : 0.f;
    if (t == 0) logZt[s * QROWS] = 0.f;
    float off = 0.f;
    __syncthreads();
    for (int ch = 0; ch < NCH; ++ch) {
      float acc = 0.f, mx = 0.f;
      if (t < 64) {
#pragma unroll 8
        for (int jj = 0; jj < 64; ++jj) acc = fmaf(mTs[jj][t], Zr[jj], acc);
        logZt[s * QROWS + ch * 64 + 1 + t] = logf(acc) + off;
        mx = acc;
#pragma unroll
        for (int o = 32; o; o >>= 1) mx = fmaxf(mx, __shfl_xor(mx, o));
      }
      __syncthreads();
      if (t < 64) {
        Zr[63 - t] = acc / mx;
        off += logf(mx);
      }
      __syncthreads();
    }
  }
}

// KB merged: blocks 0..127 = k5a_basis; blocks 128..383 = k2c (prefix fixup).
__global__ __launch_bounds__(128) void kb_basis_fix(
    const float* __restrict__ logw, const float* __restrict__ logZt,
    float* __restrict__ pig, float* __restrict__ rt, float* __restrict__ ctT,
    float* __restrict__ klocal, float* __restrict__ Q,
    const float* __restrict__ S2) {
  __shared__ __align__(16) float sbuf[16384];  // 64 KB
  __shared__ float lzs[128];
  __shared__ float lws[64];
  __shared__ float4 gsum[4][32];
  float* psd = sbuf;
  float* Pts = sbuf + 4096;
  float* Dl = sbuf + 8192;
  float* Rl = sbuf;  // stride 65, valid after scan barrier
  const int x = blockIdx.x;
  const int tid = threadIdx.x;
  if (x < 128) {
    const int s = x >> 5, ch = x & 31;
    {
      int idx = ch * 64 - 63 + tid;
      lzs[tid] = (idx >= 0) ? logZt[s * QROWS + idx] * LOG2E_F : -INFINITY;
      if (tid < 64) lws[tid] = logw[s * NLM + tid] * LOG2E_F;
    }
    __syncthreads();
    {
      const int l = tid & 63, wv = tid >> 6;
      const float lw2 = lws[l];
      for (int tt = wv; tt < 64; tt += 2) {
        float e2 = lw2 + lzs[tt + 63 - l] - lzs[tt + 64];
        float pv = __builtin_exp2f(e2);
        psd[tt * 64 + l] = pv;
        pig[((long)s * NT + ch * 64 + tt) * NLM + l] = pv;
      }
    }
    __syncthreads();
    for (int i = tid; i < 4096; i += 128) {
      int t = i >> 6, tp = i & 63;
      Pts[i] = (tp < t) ? psd[t * 64 + (t - tp - 1)] : 0.f;
    }
    for (int i = tid; i < 8192; i += 128) {
      int t = i >> 7, u = i & 127;
      float d;
      if (u < 64) {
        d = (t == u) ? 1.f : 0.f;
      } else {
        int l = t + (u - 64);
        d = (l < 64) ? psd[t * 64 + l] : 0.f;
      }
      Dl[i] = d;
    }
    __syncthreads();
    float q[4][16];
    const float* Dcol = Dl + tid;
#pragma unroll
    for (int tau = 0; tau < 4; ++tau) {
      float acc[16];
#pragma unroll
      for (int i = 0; i < 16; ++i) acc[i] = Dcol[(tau * 16 + i) * 128];
#pragma unroll
      for (int p = 0; p < 4; ++p) {
        if (p < tau) {
#pragma unroll
          for (int i = 0; i < 16; ++i) {
            const int tr = tau * 16 + i;
            float a = acc[i];
#pragma unroll
            for (int q4 = 0; q4 < 4; ++q4) {
              float4 p4 = *(const float4*)&Pts[tr * 64 + p * 16 + q4 * 4];
              a = fmaf(p4.x, q[p][4 * q4 + 0], a);
              a = fmaf(p4.y, q[p][4 * q4 + 1], a);
              a = fmaf(p4.z, q[p][4 * q4 + 2], a);
              a = fmaf(p4.w, q[p][4 * q4 + 3], a);
            }
            acc[i] = a;
          }
        }
      }
#pragma unroll
      for (int i = 0; i < 16; ++i) {
        const int tr = tau * 16 + i;
        float a = acc[i];
#pragma unroll
        for (int i2 = 0; i2 < 16; ++i2) {
          if (i2 < i) a = fmaf(Pts[tr * 64 + tau * 16 + i2], q[tau][i2], a);
        }
        q[tau][i] = a;
      }
    }
    __syncthreads();
    if (tid < 64) {
      const int tp = tid;
      float* rrow = rt + (((long)s * NCH + ch) * 64 + tp) * 64;
#pragma unroll
      for (int t4 = 0; t4 < 16; ++t4)
        ((float4*)rrow)[t4] = make_float4(
            q[t4 >> 2][4 * (t4 & 3) + 0], q[t4 >> 2][4 * (t4 & 3) + 1],
            q[t4 >> 2][4 * (t4 & 3) + 2], q[t4 >> 2][4 * (t4 & 3) + 3]);
#pragma unroll
      for (int tt = 0; tt < 4; ++tt)
#pragma unroll
        for (int i = 0; i < 16; ++i) Rl[tp * 65 + tt * 16 + i] = q[tt][i];
    } else {
      const int j = tid - 64;
      float* ctb = ctT + ((long)s * NCH + ch) * 4096;
#pragma unroll
      for (int tt = 0; tt < 4; ++tt)
#pragma unroll
        for (int i = 0; i < 16; ++i) ctb[(tt * 16 + i) * 64 + j] = q[tt][i];
    }
    __syncthreads();
    if (tid < 64) {
      float acc = 0.f;
#pragma unroll 8
      for (int tp = 0; tp < 64; ++tp) acc += Rl[tp * 65 + tid];
      klocal[((long)s * NCH + ch) * 64 + tid] = acc;
    }
  } else {
    const int y = x - 128;
    const int b = y >> 5, ch = y & 31;
    const int g = tid >> 5, c4 = tid & 31;
    if (ch == 0 && g == 0)
      ((float4*)(Q + (long)(b * QROWS) * NC))[c4] = make_float4(0.f, 0.f, 0.f, 0.f);
    float4 run = make_float4(0.f, 0.f, 0.f, 0.f);
    for (int i = 0; i < ch; ++i) {
      float4 v = ((const float4*)(S2 + (long)(b * NCH + i) * NC))[c4];
      run.x += v.x; run.y += v.y; run.z += v.z; run.w += v.w;
    }
    float4* Q4 = (float4*)(Q + (long)(b * QROWS + ch * 64 + 1) * NC);
    float4 vbuf[16];
#pragma unroll
    for (int i = 0; i < 16; ++i) vbuf[i] = Q4[(g * 16 + i) * 32 + c4];
    {
      float4 gs = make_float4(0.f, 0.f, 0.f, 0.f);
#pragma unroll
      for (int i = 0; i < 16; ++i) {
        gs.x += vbuf[i].x; gs.y += vbuf[i].y; gs.z += vbuf[i].z; gs.w += vbuf[i].w;
      }
      gsum[g][c4] = gs;
    }
    __syncthreads();
    for (int gp = 0; gp < 3; ++gp) {
      if (gp < g) {
        float4 v = gsum[gp][c4];
        run.x += v.x; run.y += v.y; run.z += v.z; run.w += v.w;
      }
    }
#pragma unroll
    for (int i = 0; i < 16; ++i) {
      run.x += vbuf[i].x; run.y += vbuf[i].y; run.z += vbuf[i].z; run.w += vbuf[i].w;
      Q4[(g * 16 + i) * 32 + c4] = run;
    }
  }
}

// K4 v6 (R23, measured): scalar-path weights via readfirstlane s_load.
__global__ __launch_bounds__(256) void k4_e(
    const float* __restrict__ Q, const float* __restrict__ pi,
    const float* __restrict__ phib, float* __restrict__ eq) {
  __shared__ float Qw[68][64];  // 17 KB
  const int b = blockIdx.x;
  const int t0 = blockIdx.y * 4;
  const int half = blockIdx.z;
  const int tid = threadIdx.x;
  for (int i = tid; i < 68 * 64; i += 256) {
    int r = i >> 6, cc = i & 63;
    int tau = t0 - 63 + r;
    Qw[r][cc] = (tau >= 0) ? Q[(b * QROWS + tau) * NC + half * 64 + cc] : 0.f;
  }
  const int c = tid & 63, tg = tid >> 6;
  const int ti = __builtin_amdgcn_readfirstlane(t0 + tg);
  const float* p0 = pi + ((long)0 * NT + ti) * NLM;
  const float* p1 = pi + ((long)1 * NT + ti) * NLM;
  const float* p2 = pi + ((long)2 * NT + ti) * NLM;
  const float* p3 = pi + ((long)3 * NT + ti) * NLM;
  __syncthreads();
  const float pb2 = phib[half * 64 + c] * TWO_LOG2E;
  const float Qt = Qw[tg + 64][c];
  float a0 = 0.f, a1 = 0.f, a2 = 0.f, a3 = 0.f;
#pragma unroll
  for (int lc = 0; lc < 4; ++lc) {
    float v[16];
#pragma unroll
    for (int u = 0; u < 16; ++u) {
      const int l = lc * 16 + u;
      const float cl = TWO_LOG2E / (float)(l + 9);
      float y = (Qt - Qw[tg + 63 - l][c]) * cl + pb2;
      v[u] = rcp_fast(exp2_fast(y) + 1.f);
    }
#pragma unroll
    for (int u = 0; u < 16; ++u) {
      const int l = lc * 16 + u;
      a0 = fmaf(p0[l], v[u], a0);
      a1 = fmaf(p1[l], v[u], a1);
      a2 = fmaf(p2[l], v[u], a2);
      a3 = fmaf(p3[l], v[u], a3);
    }
  }
  const long base = half * 64 + c;
  eq[((long)(0 * 8 + b) * NT + ti) * NC + base] = fmaf(-2.f, a0, 1.f);
  eq[((long)(1 * 8 + b) * NT + ti) * NC + base] = fmaf(-2.f, a1, 1.f);
  eq[((long)(2 * 8 + b) * NT + ti) * NC + base] = fmaf(-2.f, a2, 1.f);
  eq[((long)(3 * 8 + b) * NT + ti) * NC + base] = fmaf(-2.f, a3, 1.f);
}

// K0-prep (R30): transpose mixw -> [c][k] and split into bf16 hi/lo pairs
// for k6's MFMA path. Writes into the DEAD pi workspace.
__global__ __launch_bounds__(256) void k0_prep(
    const float* __restrict__ mixw, unsigned short* __restrict__ th,
    unsigned short* __restrict__ tl) {
  const int i = blockIdx.x * 256 + threadIdx.x;  // 0..65535
  const int k = i >> 7, c = i & 127;
  float v = mixw[i];  // mixw[k*128+c]
  unsigned short h, l;
  bf16_split(v, &h, &l);
  th[c * 512 + k] = h;
  tl[c * 512 + k] = l;
}

// K5a-data: qlocal = R @ e per (s,b,chunk) — tiled GEMM, 8t x 8c per lane.
__global__ __launch_bounds__(128) void k5a_data(const float* __restrict__ rt,
                                                float* __restrict__ eq) {
  __shared__ __align__(16) float rts[4096];    // [tp][t] 16 KB
  __shared__ __align__(16) float es[64][128];  // 32 KB
  const int sb = blockIdx.x;
  const int s = sb >> 3;
  const int ch = blockIdx.y;
  const int tid = threadIdx.x;
  const float4* rsrc = (const float4*)(rt + ((long)s * NCH + ch) * 4096);
#pragma unroll
  for (int i = 0; i < 8; ++i) ((float4*)rts)[tid + 128 * i] = rsrc[tid + 128 * i];
  float* qb = eq + ((long)sb * NT + ch * 64) * NC;
  const float4* esrc = (const float4*)qb;
#pragma unroll
  for (int i = 0; i < 16; ++i) ((float4*)es)[tid + 128 * i] = esrc[tid + 128 * i];
  __syncthreads();
  const int t0 = (tid >> 4) * 8;
  const int c0 = (tid & 15) * 8;
  float acc[8][8];
#pragma unroll
  for (int i = 0; i < 8; ++i)
#pragma unroll
    for (int k = 0; k < 8; ++k) acc[i][k] = 0.f;
  for (int tp = 0; tp < 64; ++tp) {
    if (tp <= t0 + 7) {
      float4 r0 = *(const float4*)&rts[tp * 64 + t0];
      float4 r1 = *(const float4*)&rts[tp * 64 + t0 + 4];
      float4 e0 = *(const float4*)&es[tp][c0];
      float4 e1 = *(const float4*)&es[tp][c0 + 4];
      float rr[8] = {r0.x, r0.y, r0.z, r0.w, r1.x, r1.y, r1.z, r1.w};
      float ee[8] = {e0.x, e0.y, e0.z, e0.w, e1.x, e1.y, e1.z, e1.w};
#pragma unroll
      for (int i = 0; i < 8; ++i)
#pragma unroll
        for (int k = 0; k < 8; ++k) acc[i][k] = fmaf(rr[i], ee[k], acc[i][k]);
    }
  }
#pragma unroll
  for (int i = 0; i < 8; ++i) {
    float4* dst = (float4*)(qb + (t0 + i) * NC + c0);
    dst[0] = make_float4(acc[i][0], acc[i][1], acc[i][2], acc[i][3]);
    dst[1] = make_float4(acc[i][4], acc[i][5], acc[i][6], acc[i][7]);
  }
}

// K5b v4 (R32): barrier-free register-resident scan. R31's occupancy
// doubling (9->18%) left dur pinned at 54us — the falsifier fired: the
// limiter is the 64 barriers + LDS round-trip serializing every chunk,
// not latency hiding. The waves never actually COMMUNICATE — crs was a
// shared cache. Each lane needs one 64-float ROW of cr: hold it in
// float4 cr[16] with fully STATIC indexing (R12's scratch trap was the
// runtime-indexed cast; every access here is compile-time). Zero
// barriers, zero LDS: waves run free and the compiler can pipeline
// chunk ch+1's 16 loads under chunk ch's fma chain. cr stays
// L2-resident. VGPR ~88 expected (if ~40 => spilled; revert).
__global__ __launch_bounds__(512) void k5b_scan(const float* __restrict__ ctT,
                                                const float* __restrict__ klocal,
                                                float* __restrict__ eq,
                                                float* __restrict__ kout) {
  const int tid = threadIdx.x;
  const int t = tid & 63;
  const int w = tid >> 6;  // wave 0..7
  const int bid = blockIdx.x;
  const bool isq = bid < 256;
  const int s = isq ? ((bid & 7) >> 1) : (bid - 256);
  const float* ctRow = ctT + (long)s * NCH * 4096 + t * 64;  // lane's row

  // q-branch mapping: per (s,b) 8 blocks x 8 waves x 2 channels = 128 ch
  const int g = bid >> 3;
  const int bb = g & 7, pp = g >> 3;  // pp 0..3 (q-blocks)
  const int hp = bid & 1;
  const int c0 = ((((pp << 1) | hp) << 3) | w) * 2;  // 2-float slice
  const int sb = s * 8 + bb;
  float* eqb = eq + (long)sb * NT * NC + c0;

#define K5B_J4(JJ, HVA, HVB, A0, A1, CV)                                     \
  {                                                                          \
    A0 = fmaf((CV).x, readlane_f(HVA, 63 - (4 * (JJ) + 0)), A0);             \
    A1 = fmaf((CV).x, readlane_f(HVB, 63 - (4 * (JJ) + 0)), A1);             \
    A0 = fmaf((CV).y, readlane_f(HVA, 63 - (4 * (JJ) + 1)), A0);             \
    A1 = fmaf((CV).y, readlane_f(HVB, 63 - (4 * (JJ) + 1)), A1);             \
    A0 = fmaf((CV).z, readlane_f(HVA, 63 - (4 * (JJ) + 2)), A0);             \
    A1 = fmaf((CV).z, readlane_f(HVB, 63 - (4 * (JJ) + 2)), A1);             \
    A0 = fmaf((CV).w, readlane_f(HVA, 63 - (4 * (JJ) + 3)), A0);             \
    A1 = fmaf((CV).w, readlane_f(HVB, 63 - (4 * (JJ) + 3)), A1);             \
  }

  if (isq) {
    float hv0 = 0.f, hv1 = 0.f;  // q history (per lane t)
#pragma unroll 1
    for (int ch = 0; ch < NCH; ++ch) {
      float4 cr[16];
      const float4* p = (const float4*)(ctRow + ch * 4096);
#pragma unroll
      for (int i = 0; i < 16; ++i) cr[i] = p[i];
      float2 ql = *(const float2*)(eqb + (long)(ch * 64 + t) * NC);
      float a0 = 0.f, a1 = 0.f;
#pragma unroll
      for (int jj = 0; jj < 16; ++jj) K5B_J4(jj, hv0, hv1, a0, a1, cr[jj])
      hv0 = a0 + ql.x;
      hv1 = a1 + ql.y;
      *(float2*)(eqb + (long)(ch * 64 + t) * NC) = make_float2(hv0, hv1);
    }
  } else if (tid < 64) {
    float hk = 0.f;  // k history
#pragma unroll 1
    for (int ch = 0; ch < NCH; ++ch) {
      float4 cr[16];
      const float4* p = (const float4*)(ctRow + ch * 4096);
#pragma unroll
      for (int i = 0; i < 16; ++i) cr[i] = p[i];
      float acc = klocal[((long)s * NCH + ch) * 64 + t];
#pragma unroll
      for (int jj = 0; jj < 16; ++jj) {
        float4 cv = cr[jj];
        acc = fmaf(cv.x, readlane_f(hk, 63 - (4 * jj + 0)), acc);
        acc = fmaf(cv.y, readlane_f(hk, 63 - (4 * jj + 1)), acc);
        acc = fmaf(cv.z, readlane_f(hk, 63 - (4 * jj + 2)), acc);
        acc = fmaf(cv.w, readlane_f(hk, 63 - (4 * jj + 3)), acc);
      }
      kout[s * NT + ch * 64 + t] = acc;
      hk = acc;
    }
  }
#undef K5B_J4
}

// K6 v7 (R30, measured): bf16x3 MFMA GEMM — left top-5 (<53us, was 61);
// absmax unchanged at 4.88e-4. D = Ah·Bh + Ah·Bl + Al·Bh.
__global__ __launch_bounds__(512) void k6_mix(
    const float* __restrict__ q, const float* __restrict__ kout,
    const float* __restrict__ anchor,
    const unsigned short* __restrict__ mixwTh,
    const unsigned short* __restrict__ mixwTl,
    const float* __restrict__ mixb, float* __restrict__ out) {
  __shared__ unsigned short rsh[16][520];  // 16.25 KB
  __shared__ unsigned short rsl[16][520];  // 16.25 KB
  const int b = blockIdx.x;
  const int t0 = blockIdx.y * 16;
  const int tid = threadIdx.x;
  for (int i = tid; i < 16 * 512; i += 512) {
    int r = i >> 9, sc = i & 511;
    int s = sc >> 7, c = sc & 127;
    int ti = t0 + r;
    float qv = q[((long)(s * 8 + b) * NT + ti) * NC + c];
    float kv = kout[s * NT + ti];
    float d1 = rcp_fast(kv + 16.f);
    float v = (qv + 16.f * anchor[sc]) * d1 * (kv * d1);
    unsigned short h, l;
    bf16_split(v, &h, &l);
    rsh[r][sc] = h;
    rsl[r][sc] = l;
  }
  __syncthreads();
  const int w = tid >> 6;       // wave 0..7 owns cols w*16..w*16+15
  const int lane = tid & 63;
  const int mrow = lane & 15;   // A row / B col / C col
  const int kgrp = lane >> 4;   // 0..3
  const int c0w = w * 16;
  const float bias = mixb[c0w + mrow];
  f32x4v acc = {bias, bias, bias, bias};
  const unsigned short* bh = mixwTh + (long)(c0w + mrow) * 512 + kgrp * 8;
  const unsigned short* bl = mixwTl + (long)(c0w + mrow) * 512 + kgrp * 8;
  const unsigned short* ah = &rsh[mrow][kgrp * 8];
  const unsigned short* al = &rsl[mrow][kgrp * 8];
#pragma unroll
  for (int ks = 0; ks < 16; ++ks) {
    short8v aH = *(const short8v*)(ah + ks * 32);
    short8v aL = *(const short8v*)(al + ks * 32);
    short8v bH = *(const short8v*)(bh + ks * 32);
    short8v bL = *(const short8v*)(bl + ks * 32);
    acc = __builtin_amdgcn_mfma_f32_16x16x32_bf16(aH, bH, acc, 0, 0, 0);
    acc = __builtin_amdgcn_mfma_f32_16x16x32_bf16(aH, bL, acc, 0, 0, 0);
    acc = __builtin_amdgcn_mfma_f32_16x16x32_bf16(aL, bH, acc, 0, 0, 0);
  }
  // C/D: col = lane&15, row = (lane>>4)*4 + reg
#pragma unroll
  for (int reg = 0; reg < 4; ++reg) {
    int row = kgrp * 4 + reg;
    out[((long)b * NT + t0 + row) * NC + c0w + mrow] = acc[reg];
  }
}

extern "C" void kernel_launch(void* const* d_in, const int* in_sizes, int n_in,
                              void* d_out, int out_size, void* d_ws, size_t ws_size,
                              hipStream_t stream) {
  const float* x = (const float*)d_in[0];
  const float* W = (const float*)d_in[1];
  const float* bias = (const float*)d_in[2];
  const float* phiw = (const float*)d_in[3];
  const float* phib = (const float*)d_in[4];
  const float* anchor = (const float*)d_in[5];
  const float* logw = (const float*)d_in[6];
  const float* mixw = (const float*)d_in[7];
  const float* mixb = (const float*)d_in[8];
  float* out = (float*)d_out;

  float* ws = (float*)d_ws;
  float* Q = ws;                                     // 8*2049*128 = 2,098,176
  float* pi = Q + (long)NB * QROWS * NC;             // 4*2048*64  =   524,288
  float* eq = pi + (long)NS * NT * NLM;              // 32*2048*128= 8,388,608
  float* coefTT = eq + (long)NS * NB * NT * NC;      //               524,288
  float* rtb = coefTT + (long)NS * NCH * 4096;       //               524,288
  float* klocal = rtb + (long)NS * NCH * 4096;       //                 8,192
  float* kout = klocal + (long)NS * NCH * 64;        //                 8,192
  float* logZt = kout + (long)NS * NT;               //                 8,196
  float* S2 = logZt + (long)NS * QROWS;              //                32,768

  // pi is dead after k4 — reuse as bf16 mixwT hi/lo (2 x 65536 ushorts =
  // 65536 floats <= 524288).
  unsigned short* mixwTh = (unsigned short*)pi;
  unsigned short* mixwTl = (unsigned short*)(pi + 32768);

  hipLaunchKernelGGL(k1_uv, dim3(NB * NT / 16), dim3(256), 0, stream, x, W, bias, phiw, Q);
  hipLaunchKernelGGL(k23_sums_logz, dim3(260), dim3(128), 0, stream, Q, S2, logw, logZt);
  hipLaunchKernelGGL(kb_basis_fix, dim3(384), dim3(128), 0, stream, logw, logZt, pi, rtb, coefTT, klocal, Q, S2);
  hipLaunchKernelGGL(k4_e, dim3(NB, NT / 4, 2), dim3(256), 0, stream, Q, pi, phib, eq);
  hipLaunchKernelGGL(k0_prep, dim3(256), dim3(256), 0, stream, mixw, mixwTh, mixwTl);
  hipLaunchKernelGGL(k5a_data, dim3(NS * NB, NCH), dim3(128), 0, stream, rtb, eq);
  hipLaunchKernelGGL(k5b_scan, dim3(260), dim3(512), 0, stream, coefTT, klocal, eq, kout);
  hipLaunchKernelGGL(k6_mix, dim3(NB, NT / 16), dim3(512), 0, stream, eq, kout, anchor, mixwTh, mixwTl, mixb, out);
}

// Round 21
// 330.175 us; speedup vs baseline: 1.3072x; 1.3072x over previous
//
#include <hip/hip_runtime.h>
#include <math.h>

// Problem constants
#define NB 8
#define NT 2048
#define NC 128
#define NLM 64
#define NS 4
#define QROWS 2049
#define NCH 32  // 2048 / 64 chunks

#define TWO_LOG2E 2.885390081777927f
#define LOG2E_F 1.4426950408889634f

typedef __attribute__((__ext_vector_type__(8))) short short8v;   // 8 bf16
typedef __attribute__((__ext_vector_type__(4))) float f32x4v;    // MFMA acc

__device__ __forceinline__ float rcp_fast(float x) {
  return __builtin_amdgcn_rcpf(x);
}

__device__ __forceinline__ float readlane_f(float v, int lane) {
  return __int_as_float(__builtin_amdgcn_readlane(__float_as_int(v), lane));
}

// Raw v_exp_f32 (2^x). Safe here: |y| bounded ~12.
__device__ __forceinline__ float exp2_fast(float x) {
  float r;
  asm("v_exp_f32 %0, %1" : "=v"(r) : "v"(x));
  return r;
}

// HW trig in revolutions with REQUIRED v_fract reduction (R27, verified).
__device__ __forceinline__ float fract_fast(float x) {
  float r;
  asm("v_fract_f32 %0, %1" : "=v"(r) : "v"(x));
  return r;
}
__device__ __forceinline__ float sin_rev(float r) {
  float d;
  asm("v_sin_f32 %0, %1" : "=v"(d) : "v"(r));
  return d;
}
__device__ __forceinline__ float cos_rev(float r) {
  float d;
  asm("v_cos_f32 %0, %1" : "=v"(d) : "v"(r));
  return d;
}

// bf16 hi/lo split by truncation: v = hi + lo with |err| ~ 2^-16 |v|.
__device__ __forceinline__ void bf16_split(float v, unsigned short* h,
                                           unsigned short* l) {
  unsigned vb = __float_as_uint(v);
  unsigned short hi = (unsigned short)(vb >> 16);
  float hf = __uint_as_float((unsigned)hi << 16);
  float lo = v - hf;  // exact
  *h = hi;
  *l = (unsigned short)(__float_as_uint(lo) >> 16);
}

// ---------------------------------------------------------------------------
// Tiled 64-step local linear scan (forward substitution); all indices
// compile-time so q[4][16] stays in VGPRs. (Used by k23's logZ branch.)
// ---------------------------------------------------------------------------
template <typename PF, typename DF>
__device__ __forceinline__ void tri_scan64(PF P, DF D, float q[4][16]) {
#pragma unroll
  for (int tau = 0; tau < 4; ++tau) {
    float acc[16];
#pragma unroll
    for (int i = 0; i < 16; ++i) acc[i] = D(tau * 16 + i);
#pragma unroll
    for (int p = 0; p < 4; ++p) {
      if (p < tau) {
#pragma unroll
        for (int i = 0; i < 16; ++i) {
          const int t = tau * 16 + i;
#pragma unroll
          for (int i2 = 0; i2 < 16; ++i2) {
            acc[i] = fmaf(P(t, t - (p * 16 + i2) - 1), q[p][i2], acc[i]);
          }
        }
      }
    }
#pragma unroll
    for (int i = 0; i < 16; ++i) {
      const int t = tau * 16 + i;
#pragma unroll
      for (int i2 = 0; i2 < 16; ++i2) {
        if (i2 < i) acc[i] = fmaf(P(t, i - i2 - 1), q[tau][i2], acc[i]);
      }
      q[tau][i] = acc[i];
    }
  }
}

// K1 v3 (R27, measured): R22 structure + fract-reduced HW trig.
__global__ __launch_bounds__(256) void k1_uv(
    const float* __restrict__ x, const float* __restrict__ W,
    const float* __restrict__ bias, const float* __restrict__ phiw,
    float* __restrict__ Q) {
  __shared__ __align__(16) float xs[16][128];  // 8 KB
  __shared__ float us[16][256];                // 16 KB
  const int tid = threadIdx.x;
  const int j = tid & 127;  // column
  const int h = tid >> 7;   // row-half: rows h*8 .. h*8+7
  const int r0 = h * 8;
  const int bt0 = blockIdx.x * 16;
  {
    const float4* x4 = (const float4*)(x + (long)bt0 * NC);
    ((float4*)xs)[tid] = x4[tid];
    ((float4*)xs)[tid + 256] = x4[tid + 256];
  }
  __syncthreads();
  float z[8];
  const float bj = bias[j];
#pragma unroll
  for (int r = 0; r < 8; ++r) z[r] = bj;
  for (int k = 0; k < 128; ++k) {
    float w = W[k * 128 + j];
#pragma unroll
    for (int r = 0; r < 8; ++r) z[r] = fmaf(xs[r0 + r][k], w, z[r]);
  }
  const float rs = 0.08838834764831845f;   // 1/sqrt(128)
  const float inv2pi = 0.15915494309189535f;  // 1/(2*pi)
#pragma unroll
  for (int r = 0; r < 8; ++r) {
    float rf = fract_fast(z[r] * inv2pi);  // revolutions, reduced to [0,1)
    us[r0 + r][j] = cos_rev(rf) * rs;
    us[r0 + r][128 + j] = sin_rev(rf) * rs;
  }
  __syncthreads();
  float a[8];
#pragma unroll
  for (int r = 0; r < 8; ++r) a[r] = 0.f;
  for (int k = 0; k < 256; ++k) {
    float w = phiw[k * 128 + j];
#pragma unroll
    for (int r = 0; r < 8; ++r) a[r] = fmaf(us[r0 + r][k], w, a[r]);
  }
#pragma unroll
  for (int r = 0; r < 8; ++r) {
    int bt = bt0 + r0 + r;
    int b = bt >> 11, t = bt & 2047;
    Q[(b * QROWS + t + 1) * NC + j] = a[r];
  }
}

// K23 merged: blocks 0..255 = k2a (per-chunk raw sums of V);
//             blocks 256..259 = k3ab (serial logZ chunk evolution, per s).
__global__ __launch_bounds__(128) void k23_sums_logz(
    const float* __restrict__ Q, float* __restrict__ S2,
    const float* __restrict__ logw, float* __restrict__ logZt) {
  __shared__ float4 part[4][32];
  __shared__ float wx[64];
  __shared__ float mTs[64][65];
  __shared__ float Zr[64];
  const int x = blockIdx.x;
  const int tid = threadIdx.x;
  if (x < 256) {
    const int b = x >> 5, ch = x & 31;
    const int g = tid >> 5, c4 = tid & 31;
    const float4* Q4 = (const float4*)(Q + (long)(b * QROWS + ch * 64 + 1) * NC);
    float4 acc = make_float4(0.f, 0.f, 0.f, 0.f);
#pragma unroll
    for (int i = 0; i < 16; ++i) {
      float4 v = Q4[(g * 16 + i) * 32 + c4];
      acc.x += v.x; acc.y += v.y; acc.z += v.z; acc.w += v.w;
    }
    part[g][c4] = acc;
    __syncthreads();
    if (g == 0) {
      float4 p0 = part[0][c4], p1 = part[1][c4], p2 = part[2][c4], p3 = part[3][c4];
      ((float4*)(S2 + (long)(b * NCH + ch) * NC))[c4] =
          make_float4(p0.x + p1.x + p2.x + p3.x, p0.y + p1.y + p2.y + p3.y,
                      p0.z + p1.z + p2.z + p3.z, p0.w + p1.w + p2.w + p3.w);
    }
  } else {
    const int s = x - 256;
    const int j = tid;
    if (j < 64) wx[j] = __expf(logw[s * NLM + j]);
    __syncthreads();
    if (j < 64) {
      float q[4][16];
      tri_scan64([&](int t, int l) { return wx[l]; },
                 [&](int t) { int l = t + j; return (l < 64) ? wx[l] : 0.f; }, q);
#pragma unroll
      for (int tau = 0; tau < 4; ++tau)
#pragma unroll
        for (int i = 0; i < 16; ++i) mTs[j][tau * 16 + i] = q[tau][i];
    }
    const int t = j;
    if (t < 64) Zr[t] = (t == 0) ? 1.f : 0.f;
    if (t == 0) logZt[s * QROWS] = 0.f;
    float off = 0.f;
    __syncthreads();
    for (int ch = 0; ch < NCH; ++ch) {
      float acc = 0.f, mx = 0.f;
      if (t < 64) {
#pragma unroll 8
        for (int jj = 0; jj < 64; ++jj) acc = fmaf(mTs[jj][t], Zr[jj], acc);
        logZt[s * QROWS + ch * 64 + 1 + t] = logf(acc) + off;
        mx = acc;
#pragma unroll
        for (int o = 32; o; o >>= 1) mx = fmaxf(mx, __shfl_xor(mx, o));
      }
      __syncthreads();
      if (t < 64) {
        Zr[63 - t] = acc / mx;
        off += logf(mx);
      }
      __syncthreads();
    }
  }
}

// KB merged: blocks 0..127 = k5a_basis; blocks 128..383 = k2c (prefix fixup).
__global__ __launch_bounds__(128) void kb_basis_fix(
    const float* __restrict__ logw, const float* __restrict__ logZt,
    float* __restrict__ pig, float* __restrict__ rt, float* __restrict__ ctT,
    float* __restrict__ klocal, float* __restrict__ Q,
    const float* __restrict__ S2) {
  __shared__ __align__(16) float sbuf[16384];  // 64 KB
  __shared__ float lzs[128];
  __shared__ float lws[64];
  __shared__ float4 gsum[4][32];
  float* psd = sbuf;
  float* Pts = sbuf + 4096;
  float* Dl = sbuf + 8192;
  float* Rl = sbuf;  // stride 65, valid after scan barrier
  const int x = blockIdx.x;
  const int tid = threadIdx.x;
  if (x < 128) {
    const int s = x >> 5, ch = x & 31;
    {
      int idx = ch * 64 - 63 + tid;
      lzs[tid] = (idx >= 0) ? logZt[s * QROWS + idx] * LOG2E_F : -INFINITY;
      if (tid < 64) lws[tid] = logw[s * NLM + tid] * LOG2E_F;
    }
    __syncthreads();
    {
      const int l = tid & 63, wv = tid >> 6;
      const float lw2 = lws[l];
      for (int tt = wv; tt < 64; tt += 2) {
        float e2 = lw2 + lzs[tt + 63 - l] - lzs[tt + 64];
        float pv = __builtin_exp2f(e2);
        psd[tt * 64 + l] = pv;
        pig[((long)s * NT + ch * 64 + tt) * NLM + l] = pv;
      }
    }
    __syncthreads();
    for (int i = tid; i < 4096; i += 128) {
      int t = i >> 6, tp = i & 63;
      Pts[i] = (tp < t) ? psd[t * 64 + (t - tp - 1)] : 0.f;
    }
    for (int i = tid; i < 8192; i += 128) {
      int t = i >> 7, u = i & 127;
      float d;
      if (u < 64) {
        d = (t == u) ? 1.f : 0.f;
      } else {
        int l = t + (u - 64);
        d = (l < 64) ? psd[t * 64 + l] : 0.f;
      }
      Dl[i] = d;
    }
    __syncthreads();
    float q[4][16];
    const float* Dcol = Dl + tid;
#pragma unroll
    for (int tau = 0; tau < 4; ++tau) {
      float acc[16];
#pragma unroll
      for (int i = 0; i < 16; ++i) acc[i] = Dcol[(tau * 16 + i) * 128];
#pragma unroll
      for (int p = 0; p < 4; ++p) {
        if (p < tau) {
#pragma unroll
          for (int i = 0; i < 16; ++i) {
            const int tr = tau * 16 + i;
            float a = acc[i];
#pragma unroll
            for (int q4 = 0; q4 < 4; ++q4) {
              float4 p4 = *(const float4*)&Pts[tr * 64 + p * 16 + q4 * 4];
              a = fmaf(p4.x, q[p][4 * q4 + 0], a);
              a = fmaf(p4.y, q[p][4 * q4 + 1], a);
              a = fmaf(p4.z, q[p][4 * q4 + 2], a);
              a = fmaf(p4.w, q[p][4 * q4 + 3], a);
            }
            acc[i] = a;
          }
        }
      }
#pragma unroll
      for (int i = 0; i < 16; ++i) {
        const int tr = tau * 16 + i;
        float a = acc[i];
#pragma unroll
        for (int i2 = 0; i2 < 16; ++i2) {
          if (i2 < i) a = fmaf(Pts[tr * 64 + tau * 16 + i2], q[tau][i2], a);
        }
        q[tau][i] = a;
      }
    }
    __syncthreads();
    if (tid < 64) {
      const int tp = tid;
      float* rrow = rt + (((long)s * NCH + ch) * 64 + tp) * 64;
#pragma unroll
      for (int t4 = 0; t4 < 16; ++t4)
        ((float4*)rrow)[t4] = make_float4(
            q[t4 >> 2][4 * (t4 & 3) + 0], q[t4 >> 2][4 * (t4 & 3) + 1],
            q[t4 >> 2][4 * (t4 & 3) + 2], q[t4 >> 2][4 * (t4 & 3) + 3]);
#pragma unroll
      for (int tt = 0; tt < 4; ++tt)
#pragma unroll
        for (int i = 0; i < 16; ++i) Rl[tp * 65 + tt * 16 + i] = q[tt][i];
    } else {
      const int j = tid - 64;
      float* ctb = ctT + ((long)s * NCH + ch) * 4096;
#pragma unroll
      for (int tt = 0; tt < 4; ++tt)
#pragma unroll
        for (int i = 0; i < 16; ++i) ctb[(tt * 16 + i) * 64 + j] = q[tt][i];
    }
    __syncthreads();
    if (tid < 64) {
      float acc = 0.f;
#pragma unroll 8
      for (int tp = 0; tp < 64; ++tp) acc += Rl[tp * 65 + tid];
      klocal[((long)s * NCH + ch) * 64 + tid] = acc;
    }
  } else {
    const int y = x - 128;
    const int b = y >> 5, ch = y & 31;
    const int g = tid >> 5, c4 = tid & 31;
    if (ch == 0 && g == 0)
      ((float4*)(Q + (long)(b * QROWS) * NC))[c4] = make_float4(0.f, 0.f, 0.f, 0.f);
    float4 run = make_float4(0.f, 0.f, 0.f, 0.f);
    for (int i = 0; i < ch; ++i) {
      float4 v = ((const float4*)(S2 + (long)(b * NCH + i) * NC))[c4];
      run.x += v.x; run.y += v.y; run.z += v.z; run.w += v.w;
    }
    float4* Q4 = (float4*)(Q + (long)(b * QROWS + ch * 64 + 1) * NC);
    float4 vbuf[16];
#pragma unroll
    for (int i = 0; i < 16; ++i) vbuf[i] = Q4[(g * 16 + i) * 32 + c4];
    {
      float4 gs = make_float4(0.f, 0.f, 0.f, 0.f);
#pragma unroll
      for (int i = 0; i < 16; ++i) {
        gs.x += vbuf[i].x; gs.y += vbuf[i].y; gs.z += vbuf[i].z; gs.w += vbuf[i].w;
      }
      gsum[g][c4] = gs;
    }
    __syncthreads();
    for (int gp = 0; gp < 3; ++gp) {
      if (gp < g) {
        float4 v = gsum[gp][c4];
        run.x += v.x; run.y += v.y; run.z += v.z; run.w += v.w;
      }
    }
#pragma unroll
    for (int i = 0; i < 16; ++i) {
      run.x += vbuf[i].x; run.y += vbuf[i].y; run.z += vbuf[i].z; run.w += vbuf[i].w;
      Q4[(g * 16 + i) * 32 + c4] = run;
    }
  }
}

// K4 v6 (R23, measured): scalar-path weights via readfirstlane s_load.
__global__ __launch_bounds__(256) void k4_e(
    const float* __restrict__ Q, const float* __restrict__ pi,
    const float* __restrict__ phib, float* __restrict__ eq) {
  __shared__ float Qw[68][64];  // 17 KB
  const int b = blockIdx.x;
  const int t0 = blockIdx.y * 4;
  const int half = blockIdx.z;
  const int tid = threadIdx.x;
  for (int i = tid; i < 68 * 64; i += 256) {
    int r = i >> 6, cc = i & 63;
    int tau = t0 - 63 + r;
    Qw[r][cc] = (tau >= 0) ? Q[(b * QROWS + tau) * NC + half * 64 + cc] : 0.f;
  }
  const int c = tid & 63, tg = tid >> 6;
  const int ti = __builtin_amdgcn_readfirstlane(t0 + tg);
  const float* p0 = pi + ((long)0 * NT + ti) * NLM;
  const float* p1 = pi + ((long)1 * NT + ti) * NLM;
  const float* p2 = pi + ((long)2 * NT + ti) * NLM;
  const float* p3 = pi + ((long)3 * NT + ti) * NLM;
  __syncthreads();
  const float pb2 = phib[half * 64 + c] * TWO_LOG2E;
  const float Qt = Qw[tg + 64][c];
  float a0 = 0.f, a1 = 0.f, a2 = 0.f, a3 = 0.f;
#pragma unroll
  for (int lc = 0; lc < 4; ++lc) {
    float v[16];
#pragma unroll
    for (int u = 0; u < 16; ++u) {
      const int l = lc * 16 + u;
      const float cl = TWO_LOG2E / (float)(l + 9);
      float y = (Qt - Qw[tg + 63 - l][c]) * cl + pb2;
      v[u] = rcp_fast(exp2_fast(y) + 1.f);
    }
#pragma unroll
    for (int u = 0; u < 16; ++u) {
      const int l = lc * 16 + u;
      a0 = fmaf(p0[l], v[u], a0);
      a1 = fmaf(p1[l], v[u], a1);
      a2 = fmaf(p2[l], v[u], a2);
      a3 = fmaf(p3[l], v[u], a3);
    }
  }
  const long base = half * 64 + c;
  eq[((long)(0 * 8 + b) * NT + ti) * NC + base] = fmaf(-2.f, a0, 1.f);
  eq[((long)(1 * 8 + b) * NT + ti) * NC + base] = fmaf(-2.f, a1, 1.f);
  eq[((long)(2 * 8 + b) * NT + ti) * NC + base] = fmaf(-2.f, a2, 1.f);
  eq[((long)(3 * 8 + b) * NT + ti) * NC + base] = fmaf(-2.f, a3, 1.f);
}

// K0-prep (R30): transpose mixw -> [c][k] and split into bf16 hi/lo pairs
// for k6's MFMA path. Writes into the DEAD pi workspace.
__global__ __launch_bounds__(256) void k0_prep(
    const float* __restrict__ mixw, unsigned short* __restrict__ th,
    unsigned short* __restrict__ tl) {
  const int i = blockIdx.x * 256 + threadIdx.x;  // 0..65535
  const int k = i >> 7, c = i & 127;
  float v = mixw[i];  // mixw[k*128+c]
  unsigned short h, l;
  bf16_split(v, &h, &l);
  th[c * 512 + k] = h;
  tl[c * 512 + k] = l;
}

// K5a-data: qlocal = R @ e per (s,b,chunk) — tiled GEMM, 8t x 8c per lane.
__global__ __launch_bounds__(128) void k5a_data(const float* __restrict__ rt,
                                                float* __restrict__ eq) {
  __shared__ __align__(16) float rts[4096];    // [tp][t] 16 KB
  __shared__ __align__(16) float es[64][128];  // 32 KB
  const int sb = blockIdx.x;
  const int s = sb >> 3;
  const int ch = blockIdx.y;
  const int tid = threadIdx.x;
  const float4* rsrc = (const float4*)(rt + ((long)s * NCH + ch) * 4096);
#pragma unroll
  for (int i = 0; i < 8; ++i) ((float4*)rts)[tid + 128 * i] = rsrc[tid + 128 * i];
  float* qb = eq + ((long)sb * NT + ch * 64) * NC;
  const float4* esrc = (const float4*)qb;
#pragma unroll
  for (int i = 0; i < 16; ++i) ((float4*)es)[tid + 128 * i] = esrc[tid + 128 * i];
  __syncthreads();
  const int t0 = (tid >> 4) * 8;
  const int c0 = (tid & 15) * 8;
  float acc[8][8];
#pragma unroll
  for (int i = 0; i < 8; ++i)
#pragma unroll
    for (int k = 0; k < 8; ++k) acc[i][k] = 0.f;
  for (int tp = 0; tp < 64; ++tp) {
    if (tp <= t0 + 7) {
      float4 r0 = *(const float4*)&rts[tp * 64 + t0];
      float4 r1 = *(const float4*)&rts[tp * 64 + t0 + 4];
      float4 e0 = *(const float4*)&es[tp][c0];
      float4 e1 = *(const float4*)&es[tp][c0 + 4];
      float rr[8] = {r0.x, r0.y, r0.z, r0.w, r1.x, r1.y, r1.z, r1.w};
      float ee[8] = {e0.x, e0.y, e0.z, e0.w, e1.x, e1.y, e1.z, e1.w};
#pragma unroll
      for (int i = 0; i < 8; ++i)
#pragma unroll
        for (int k = 0; k < 8; ++k) acc[i][k] = fmaf(rr[i], ee[k], acc[i][k]);
    }
  }
#pragma unroll
  for (int i = 0; i < 8; ++i) {
    float4* dst = (float4*)(qb + (t0 + i) * NC + c0);
    dst[0] = make_float4(acc[i][0], acc[i][1], acc[i][2], acc[i][3]);
    dst[1] = make_float4(acc[i][4], acc[i][5], acc[i][6], acc[i][7]);
  }
}

// K5b v2 (R30 config, RESTORED in R33): cross-chunk combine; cr chunk
// staged per block through padded LDS (stride 65 => conflict-free),
// double-buffered; 4 waves x 4 channels. History via v_readlane.
// Measured 53.6us. R31 (8 waves) = 54.2; R32 (register-resident,
// barrier-free) = 156 (cr spilled: VGPR=32 fingerprint fired). Both
// falsifiers fired => 53.6 is this formulation's structural floor,
// bounded by the serial cross-chunk dependency chain.
__global__ __launch_bounds__(256) void k5b_scan(const float* __restrict__ ctT,
                                                const float* __restrict__ klocal,
                                                float* __restrict__ eq,
                                                float* __restrict__ kout) {
  __shared__ float crs[2][64 * 65];  // 32.5 KB, padded stride 65
  const int tid = threadIdx.x;
  const int t = tid & 63;
  const int w = tid >> 6;
  const int bid = blockIdx.x;
  const bool isq = bid < 256;
  const int s = isq ? ((bid & 7) >> 1) : (bid - 256);
  const float* ctTs = ctT + (long)s * NCH * 4096;

  // staging geometry: thread -> (row sr, 16-float quarter sq); 16 floats each
  const int sr = tid >> 2;
  const int sq = (tid & 3) * 16;
  float4 stg0, stg1, stg2, stg3;

#define K5B_STAGE_LOAD(CH)                                                    \
  {                                                                           \
    const float4* p_ = (const float4*)(ctTs + (CH)*4096 + sr * 64 + sq);      \
    stg0 = p_[0]; stg1 = p_[1]; stg2 = p_[2]; stg3 = p_[3];                   \
  }
#define K5B_STAGE_WRITE(BUF)                                                  \
  {                                                                           \
    float* d_ = &crs[BUF][sr * 65 + sq];                                      \
    d_[0] = stg0.x;  d_[1] = stg0.y;  d_[2] = stg0.z;  d_[3] = stg0.w;        \
    d_[4] = stg1.x;  d_[5] = stg1.y;  d_[6] = stg1.z;  d_[7] = stg1.w;        \
    d_[8] = stg2.x;  d_[9] = stg2.y;  d_[10] = stg2.z; d_[11] = stg2.w;       \
    d_[12] = stg3.x; d_[13] = stg3.y; d_[14] = stg3.z; d_[15] = stg3.w;       \
  }

  // q-branch mapping: per (s,b) 8 blocks x 4 waves x 4 channels = 128 ch
  const int g = bid >> 3;
  const int bb = g & 7, pp = g >> 3;  // pp 0..3 (q-blocks)
  const int hp = bid & 1;
  const int c0 = ((((pp << 1) | hp) << 2) | w) * 4;  // slice*4, slice 0..31
  const int sb = s * 8 + bb;
  float* eqb = eq + (long)sb * NT * NC + c0;

  float hv0 = 0.f, hv1 = 0.f, hv2 = 0.f, hv3 = 0.f;  // q history (per lane t)
  float hk = 0.f;                                    // k history

  K5B_STAGE_LOAD(0)
  K5B_STAGE_WRITE(0)
  __syncthreads();
#pragma unroll 1
  for (int ch = 0; ch < NCH; ++ch) {
    const int cur = ch & 1;
    if (ch + 1 < NCH) K5B_STAGE_LOAD(ch + 1)  // issue early; lands at write
    if (isq) {
      const float* cr = &crs[cur][t * 65];
      float4 ql = *(const float4*)(eqb + (long)(ch * 64 + t) * NC);
      float a0 = 0.f, a1 = 0.f, a2 = 0.f, a3 = 0.f;
#pragma unroll
      for (int j = 0; j < 64; ++j) {
        float cv = cr[j];
        a0 = fmaf(cv, readlane_f(hv0, 63 - j), a0);
        a1 = fmaf(cv, readlane_f(hv1, 63 - j), a1);
        a2 = fmaf(cv, readlane_f(hv2, 63 - j), a2);
        a3 = fmaf(cv, readlane_f(hv3, 63 - j), a3);
      }
      hv0 = a0 + ql.x; hv1 = a1 + ql.y; hv2 = a2 + ql.z; hv3 = a3 + ql.w;
      *(float4*)(eqb + (long)(ch * 64 + t) * NC) =
          make_float4(hv0, hv1, hv2, hv3);
    } else if (tid < 64) {
      const float* cr = &crs[cur][t * 65];
      float acc = klocal[((long)s * NCH + ch) * 64 + t];
#pragma unroll
      for (int j = 0; j < 64; ++j)
        acc = fmaf(cr[j], readlane_f(hk, 63 - j), acc);
      kout[s * NT + ch * 64 + t] = acc;
      hk = acc;
    }
    __syncthreads();  // all waves done READING crs[cur^1] (chunk ch-1)
    if (ch + 1 < NCH) K5B_STAGE_WRITE(cur ^ 1)
    __syncthreads();  // crs[cur^1] ready for chunk ch+1
  }
#undef K5B_STAGE_LOAD
#undef K5B_STAGE_WRITE
}

// K6 v7 (R30, measured): bf16x3 MFMA GEMM — left top-5 (<53us, was 61);
// absmax unchanged at 4.88e-4. D = Ah·Bh + Ah·Bl + Al·Bh.
__global__ __launch_bounds__(512) void k6_mix(
    const float* __restrict__ q, const float* __restrict__ kout,
    const float* __restrict__ anchor,
    const unsigned short* __restrict__ mixwTh,
    const unsigned short* __restrict__ mixwTl,
    const float* __restrict__ mixb, float* __restrict__ out) {
  __shared__ unsigned short rsh[16][520];  // 16.25 KB
  __shared__ unsigned short rsl[16][520];  // 16.25 KB
  const int b = blockIdx.x;
  const int t0 = blockIdx.y * 16;
  const int tid = threadIdx.x;
  for (int i = tid; i < 16 * 512; i += 512) {
    int r = i >> 9, sc = i & 511;
    int s = sc >> 7, c = sc & 127;
    int ti = t0 + r;
    float qv = q[((long)(s * 8 + b) * NT + ti) * NC + c];
    float kv = kout[s * NT + ti];
    float d1 = rcp_fast(kv + 16.f);
    float v = (qv + 16.f * anchor[sc]) * d1 * (kv * d1);
    unsigned short h, l;
    bf16_split(v, &h, &l);
    rsh[r][sc] = h;
    rsl[r][sc] = l;
  }
  __syncthreads();
  const int w = tid >> 6;       // wave 0..7 owns cols w*16..w*16+15
  const int lane = tid & 63;
  const int mrow = lane & 15;   // A row / B col / C col
  const int kgrp = lane >> 4;   // 0..3
  const int c0w = w * 16;
  const float bias = mixb[c0w + mrow];
  f32x4v acc = {bias, bias, bias, bias};
  const unsigned short* bh = mixwTh + (long)(c0w + mrow) * 512 + kgrp * 8;
  const unsigned short* bl = mixwTl + (long)(c0w + mrow) * 512 + kgrp * 8;
  const unsigned short* ah = &rsh[mrow][kgrp * 8];
  const unsigned short* al = &rsl[mrow][kgrp * 8];
#pragma unroll
  for (int ks = 0; ks < 16; ++ks) {
    short8v aH = *(const short8v*)(ah + ks * 32);
    short8v aL = *(const short8v*)(al + ks * 32);
    short8v bH = *(const short8v*)(bh + ks * 32);
    short8v bL = *(const short8v*)(bl + ks * 32);
    acc = __builtin_amdgcn_mfma_f32_16x16x32_bf16(aH, bH, acc, 0, 0, 0);
    acc = __builtin_amdgcn_mfma_f32_16x16x32_bf16(aH, bL, acc, 0, 0, 0);
    acc = __builtin_amdgcn_mfma_f32_16x16x32_bf16(aL, bH, acc, 0, 0, 0);
  }
  // C/D: col = lane&15, row = (lane>>4)*4 + reg
#pragma unroll
  for (int reg = 0; reg < 4; ++reg) {
    int row = kgrp * 4 + reg;
    out[((long)b * NT + t0 + row) * NC + c0w + mrow] = acc[reg];
  }
}

extern "C" void kernel_launch(void* const* d_in, const int* in_sizes, int n_in,
                              void* d_out, int out_size, void* d_ws, size_t ws_size,
                              hipStream_t stream) {
  const float* x = (const float*)d_in[0];
  const float* W = (const float*)d_in[1];
  const float* bias = (const float*)d_in[2];
  const float* phiw = (const float*)d_in[3];
  const float* phib = (const float*)d_in[4];
  const float* anchor = (const float*)d_in[5];
  const float* logw = (const float*)d_in[6];
  const float* mixw = (const float*)d_in[7];
  const float* mixb = (const float*)d_in[8];
  float* out = (float*)d_out;

  float* ws = (float*)d_ws;
  float* Q = ws;                                     // 8*2049*128 = 2,098,176
  float* pi = Q + (long)NB * QROWS * NC;             // 4*2048*64  =   524,288
  float* eq = pi + (long)NS * NT * NLM;              // 32*2048*128= 8,388,608
  float* coefTT = eq + (long)NS * NB * NT * NC;      //               524,288
  float* rtb = coefTT + (long)NS * NCH * 4096;       //               524,288
  float* klocal = rtb + (long)NS * NCH * 4096;       //                 8,192
  float* kout = klocal + (long)NS * NCH * 64;        //                 8,192
  float* logZt = kout + (long)NS * NT;               //                 8,196
  float* S2 = logZt + (long)NS * QROWS;              //                32,768

  // pi is dead after k4 — reuse as bf16 mixwT hi/lo (2 x 65536 ushorts =
  // 65536 floats <= 524288).
  unsigned short* mixwTh = (unsigned short*)pi;
  unsigned short* mixwTl = (unsigned short*)(pi + 32768);

  hipLaunchKernelGGL(k1_uv, dim3(NB * NT / 16), dim3(256), 0, stream, x, W, bias, phiw, Q);
  hipLaunchKernelGGL(k23_sums_logz, dim3(260), dim3(128), 0, stream, Q, S2, logw, logZt);
  hipLaunchKernelGGL(kb_basis_fix, dim3(384), dim3(128), 0, stream, logw, logZt, pi, rtb, coefTT, klocal, Q, S2);
  hipLaunchKernelGGL(k4_e, dim3(NB, NT / 4, 2), dim3(256), 0, stream, Q, pi, phib, eq);
  hipLaunchKernelGGL(k0_prep, dim3(256), dim3(256), 0, stream, mixw, mixwTh, mixwTl);
  hipLaunchKernelGGL(k5a_data, dim3(NS * NB, NCH), dim3(128), 0, stream, rtb, eq);
  hipLaunchKernelGGL(k5b_scan, dim3(260), dim3(256), 0, stream, coefTT, klocal, eq, kout);
  hipLaunchKernelGGL(k6_mix, dim3(NB, NT / 16), dim3(512), 0, stream, eq, kout, anchor, mixwTh, mixwTl, mixb, out);
}